// Round 1
// baseline (124.950 us; speedup 1.0000x reference)
//
#include <hip/hip_runtime.h>

// ScoringAlignedContinuousLoss — B=4M, R=32 rungs, T=10.
// Windowed sigmoid-ladder evaluation: only rungs within floor(p)±3 contribute
// above 1e-13 relative (T=10 => neighbor decay e^-10 per rung). One exp2 +
// 9 rcp per element instead of 33 exp + 33 rcp.

#if __has_builtin(__builtin_amdgcn_exp2f)
#define FAST_EXP2(x) __builtin_amdgcn_exp2f(x)
#else
#define FAST_EXP2(x) exp2f(x)
#endif

#define FAST_RCP(x) __builtin_amdgcn_rcpf(x)

// e^{-10*j} for j = -3..4  (u_{f+j} = u_c * EXPTAB[j+3]); all fp32-representable
__constant__ float EXPTAB[8] = {
    1.0686474581524463e13f,   // e^{30}
    4.8516519540979028e8f,    // e^{20}
    2.2026465794806718e4f,    // e^{10}
    1.0f,                     // e^{0}
    4.5399929762484854e-5f,   // e^{-10}
    2.0611536224385580e-9f,   // e^{-20}
    9.3576229688401746e-14f,  // e^{-30}
    4.2483542552915889e-18f   // e^{-40}
};

__device__ __forceinline__ float elem_loss(float p, float t) {
    const float K = 14.426950408889634f;  // 10 * log2(e)

    // t_idx = clip(searchsorted(ladder, clip(t,1,32)), 0, 31) == clip(ceil(tc)-1, 0, 31)
    float tc = fminf(fmaxf(t, 1.0f), 32.0f);
    int tidx = (int)ceilf(tc) - 1;
    tidx = min(max(tidx, 0), 31);

    float fp = floorf(p);
    int f = (int)fp;

    // u_c = e^{10*(p - f)} in [1, e^10]
    float uc = FAST_EXP2(K * (p - fp));

    // q_k = 1/(1 + u_{f-3+k}) = sigmoid(10*((f-3+k) - p + ... ))  [second factor]
    // s_lo_{f-3+k} = 1 - q_k                                      [first factor]
    float q[8];
#pragma unroll
    for (int k = 0; k < 8; ++k) {
        q[k] = FAST_RCP(fmaf(uc, EXPTAB[k], 1.0f));
    }

    float num = 0.0f, den = 0.0f;
    int base = f - 3 - tidx;  // d at k=0
#pragma unroll
    for (int k = 0; k < 7; ++k) {
        int r = f - 3 + k;
        float prob = (1.0f - q[k]) * q[k + 1];
        prob = (r >= 0 && r < 32) ? prob : 0.0f;
        int d = base + k;  // r - tidx, range [-34, 35]
        float sc = (d >= 0) ? __int_as_float((127 - d) << 23) : 0.0f;  // 2^{-d}
        num = fmaf(prob, sc, num);
        den += prob;
    }

    float dd = den + 1e-8f;
    // rcp + one Newton step for ~0.5 ulp division
    float r0 = FAST_RCP(dd);
    r0 = fmaf(r0, fmaf(-dd, r0, 1.0f), r0);
    return 1.0f - num * r0;
}

__global__ __launch_bounds__(256) void sacl_kernel(
    const float* __restrict__ pred, const float* __restrict__ target,
    float* __restrict__ out, double* __restrict__ wsum,
    unsigned int* __restrict__ wcnt, int n) {
    int tid = blockIdx.x * blockDim.x + threadIdx.x;
    int nth = gridDim.x * blockDim.x;

    float acc = 0.0f;
    int nv = n >> 2;
    const float4* p4 = (const float4*)pred;
    const float4* t4 = (const float4*)target;
    for (int i = tid; i < nv; i += nth) {
        float4 pv = p4[i];
        float4 tv = t4[i];
        acc += elem_loss(pv.x, tv.x);
        acc += elem_loss(pv.y, tv.y);
        acc += elem_loss(pv.z, tv.z);
        acc += elem_loss(pv.w, tv.w);
    }
    for (int i = (nv << 2) + tid; i < n; i += nth)  // tail (none for B=4M)
        acc += elem_loss(pred[i], target[i]);

    // wave64 reduce
#pragma unroll
    for (int off = 32; off > 0; off >>= 1) acc += __shfl_down(acc, off, 64);

    __shared__ float part[4];
    int lane = threadIdx.x & 63;
    int wid = threadIdx.x >> 6;
    if (lane == 0) part[wid] = acc;
    __syncthreads();

    if (threadIdx.x == 0) {
        double s = (double)part[0] + (double)part[1] + (double)part[2] + (double)part[3];
        atomicAdd(wsum, s);
        __threadfence();
        unsigned int old = atomicAdd(wcnt, 1u);
        if (old == gridDim.x - 1) {
            double tot = atomicAdd(wsum, 0.0);  // atomic read-back of full sum
            out[0] = (float)(tot / (double)n);
        }
    }
}

extern "C" void kernel_launch(void* const* d_in, const int* in_sizes, int n_in,
                              void* d_out, int out_size, void* d_ws, size_t ws_size,
                              hipStream_t stream) {
    const float* pred = (const float*)d_in[0];
    const float* target = (const float*)d_in[1];
    int n = in_sizes[0];
    float* out = (float*)d_out;
    double* wsum = (double*)d_ws;
    unsigned int* wcnt = (unsigned int*)((char*)d_ws + sizeof(double));

    // ws is poisoned 0xAA before every launch — zero the accumulator + counter.
    hipMemsetAsync(d_ws, 0, 16, stream);

    const int block = 256;
    const int grid = 2048;
    sacl_kernel<<<grid, block, 0, stream>>>(pred, target, out, wsum, wcnt, n);
}

// Round 3
// 81.174 us; speedup vs baseline: 1.5393x; 1.5393x over previous
//
#include <hip/hip_runtime.h>

// ScoringAlignedContinuousLoss — B=4M, R=32 rungs, T=10.
// Windowed sigmoid-ladder: rungs beyond floor(p)±2 carry <= e^-20 relative
// mass (T=10 decay), below fp32 rounding. 1 exp2 + 7 rcp per element.
// Reduction: per-block plain-store partials (NO same-address atomics — R1
// showed a 2048-way fp64 atomic tail storm: VALUBusy 15%, occ 31%) +
// single-block finish kernel (NO hipMemsetAsync in the graph).

#define FAST_EXP2(x) __builtin_amdgcn_exp2f(x)
#define FAST_RCP(x) __builtin_amdgcn_rcpf(x)

__device__ __forceinline__ float elem_loss(float p, float t) {
    const float K = 14.426950408889634f;  // 10 * log2(e)

    // t_idx = clip(searchsorted(ladder, clip(t,1,32)), 0, 31) == clip(ceil(tc)-1, 0, 31)
    float tc = fminf(fmaxf(t, 1.0f), 32.0f);
    int tidx = min(max((int)ceilf(tc) - 1, 0), 31);

    float fp = floorf(p);
    int f = (int)fp;

    // u_c = e^{10*(p-f)} in [1, e^10); u_{f-2+k} = u_c * e^{-10*(k-2)}
    float uc = FAST_EXP2(K * (p - fp));

    // q[k] = sigmoid(10*((f-2+k) - p)); rung prob[r=f-2+k] = (1-q[k])*q[k+1]
    const float etab[6] = {4.8516519540979028e8f,   // e^{20}
                           2.2026465794806718e4f,   // e^{10}
                           1.0f,                    // e^{0}
                           4.5399929762484854e-5f,  // e^{-10}
                           2.0611536224385580e-9f,  // e^{-20}
                           9.3576229688401746e-14f};// e^{-30}
    float q[6];
#pragma unroll
    for (int k = 0; k < 6; ++k) q[k] = FAST_RCP(fmaf(uc, etab[k], 1.0f));

    float num = 0.0f, den = 0.0f;
    int base = f - 2 - tidx;
#pragma unroll
    for (int k = 0; k < 5; ++k) {
        int r = f - 2 + k;
        float prob = (1.0f - q[k]) * q[k + 1];
        prob = ((unsigned)r < 32u) ? prob : 0.0f;  // rungs 0..31 only
        int d = base + k;                          // r - tidx in [-33, 34]
        float sc = (d >= 0) ? __int_as_float((127 - d) << 23) : 0.0f;  // 2^{-d}
        num = fmaf(prob, sc, num);
        den += prob;
    }

    float dd = den + 1e-8f;
    float r0 = FAST_RCP(dd);
    r0 = fmaf(r0, fmaf(-dd, r0, 1.0f), r0);  // Newton: ~0.5 ulp divide
    return 1.0f - num * r0;
}

__global__ __launch_bounds__(256) void sacl_partial(
    const float* __restrict__ pred, const float* __restrict__ target,
    double* __restrict__ partial, int n) {
    int tid = blockIdx.x * blockDim.x + threadIdx.x;
    int nth = gridDim.x * blockDim.x;

    float acc = 0.0f;
    int nv = n >> 2;
    const float4* p4 = (const float4*)pred;
    const float4* t4 = (const float4*)target;
    for (int i = tid; i < nv; i += nth) {
        float4 pv = p4[i];
        float4 tv = t4[i];
        acc += elem_loss(pv.x, tv.x);
        acc += elem_loss(pv.y, tv.y);
        acc += elem_loss(pv.z, tv.z);
        acc += elem_loss(pv.w, tv.w);
    }
    for (int i = (nv << 2) + tid; i < n; i += nth)  // tail (none for B=4M)
        acc += elem_loss(pred[i], target[i]);

    // wave64 reduce
#pragma unroll
    for (int off = 32; off > 0; off >>= 1) acc += __shfl_down(acc, off, 64);

    __shared__ float part[4];
    int lane = threadIdx.x & 63;
    int wid = threadIdx.x >> 6;
    if (lane == 0) part[wid] = acc;
    __syncthreads();

    if (threadIdx.x == 0) {
        partial[blockIdx.x] =
            (double)part[0] + (double)part[1] + (double)part[2] + (double)part[3];
    }
}

__global__ __launch_bounds__(256) void sacl_final(
    const double* __restrict__ partial, int g, float* __restrict__ out, int n) {
    double s = 0.0;
    for (int i = threadIdx.x; i < g; i += 256) s += partial[i];

#pragma unroll
    for (int off = 32; off > 0; off >>= 1) s += __shfl_down(s, off, 64);

    __shared__ double sm[4];
    int lane = threadIdx.x & 63;
    int wid = threadIdx.x >> 6;
    if (lane == 0) sm[wid] = s;
    __syncthreads();

    if (threadIdx.x == 0)
        out[0] = (float)((sm[0] + sm[1] + sm[2] + sm[3]) / (double)n);
}

extern "C" void kernel_launch(void* const* d_in, const int* in_sizes, int n_in,
                              void* d_out, int out_size, void* d_ws, size_t ws_size,
                              hipStream_t stream) {
    const float* pred = (const float*)d_in[0];
    const float* target = (const float*)d_in[1];
    int n = in_sizes[0];
    float* out = (float*)d_out;
    double* partial = (double*)d_ws;  // grid doubles; every slot written before read

    const int block = 256;
    const int grid = 2048;
    sacl_partial<<<grid, block, 0, stream>>>(pred, target, partial, n);
    sacl_final<<<1, block, 0, stream>>>(partial, grid, out, n);
}

// Round 4
// 79.797 us; speedup vs baseline: 1.5659x; 1.0173x over previous
//
#include <hip/hip_runtime.h>

// ScoringAlignedContinuousLoss — B=4M, R=32 rungs, T=10.
// Windowed sigmoid-ladder: rungs beyond floor(p)±2 carry <= e^-20 relative
// mass. Endpoint sigmoids are saturated (q0<=2e-9, q5>=1-2e-9), so only 4
// interior sigmoids are computed: 1 exp2 + 5 rcp per element total.
// Scores folded into branchless constant-coefficient FMAs:
//   num = 2^{m2} * sum_k p_k 2^{-k} [k >= m2],  m2 = tidx - f + 2.
// Reduction: per-block plain-store fp64 partials (NO same-address atomics —
// R1 showed a 2048-way fp64 atomic tail storm) + single-block finish.
// NOTE (R3 counters): harness re-poison of 256MB d_ws (~43us fill at 6.2TB/s)
// + 32MB input restore (~10us) are in the timed path — fixed floor ~55us.

#define FAST_EXP2(x) __builtin_amdgcn_exp2f(x)
#define FAST_RCP(x) __builtin_amdgcn_rcpf(x)

__device__ __forceinline__ float elem_loss(float p, float t) {
    const float K = 14.426950408889634f;  // 10 * log2(e)

    // t_idx = searchsorted(ladder=1..32, clip(t,1,32)) == ceil(tc)-1, in [0,31]
    float tc = fminf(fmaxf(t, 1.0f), 32.0f);
    int tidx = (int)ceilf(tc) - 1;

    float fp = floorf(p);
    int f = (int)fp;                                  // f in [0,32] for p in (0,33)
    float uc = FAST_EXP2(K * (p - fp));               // e^{10*frac} in [1, e^10)

    // q_k = sigmoid(10*((f-2+k) - p)), k=1..4 (k=0 ~ 0, k=5 ~ 1, saturated)
    float q1 = FAST_RCP(fmaf(uc, 2.2026465794806718e4f, 1.0f));   // e^{10}
    float q2 = FAST_RCP(uc + 1.0f);
    float q3 = FAST_RCP(fmaf(uc, 4.5399929762484854e-5f, 1.0f));  // e^{-10}
    float q4 = FAST_RCP(fmaf(uc, 2.0611536224385580e-9f, 1.0f));  // e^{-20}

    // rung probs for r = f-2 .. f+2:  prob_r = s_r*(1-s_{r+1}) = (1-q_k)*q_{k+1}
    float p0 = q1;
    float p1 = (1.0f - q1) * q2;
    float p2 = (1.0f - q2) * q3;
    float p3 = (1.0f - q3) * q4;
    float p4 = 1.0f - q4;

    // mask rungs outside [0,31]
    p0 = ((unsigned)(f - 2) < 32u) ? p0 : 0.0f;
    p1 = ((unsigned)(f - 1) < 32u) ? p1 : 0.0f;
    p2 = ((unsigned)(f    ) < 32u) ? p2 : 0.0f;
    p3 = ((unsigned)(f + 1) < 32u) ? p3 : 0.0f;
    p4 = ((unsigned)(f + 2) < 32u) ? p4 : 0.0f;

    float den = p0 + p1 + p2 + p3 + p4;

    // score(r) = 2^{-(r - tidx)} for r >= tidx; d_k = k - m2
    int m2 = tidx - f + 2;                            // threshold: k >= m2
    float num = 0.0f;
    num = fmaf(p0, (m2 <= 0) ? 1.0f    : 0.0f, num);
    num = fmaf(p1, (m2 <= 1) ? 0.5f    : 0.0f, num);
    num = fmaf(p2, (m2 <= 2) ? 0.25f   : 0.0f, num);
    num = fmaf(p3, (m2 <= 3) ? 0.125f  : 0.0f, num);
    num = fmaf(p4, (m2 <= 4) ? 0.0625f : 0.0f, num);
    num *= __int_as_float((127 + m2) << 23);          // * 2^{m2}; exp in [97,160]

    float dd = den + 1e-8f;
    float r0 = FAST_RCP(dd);
    r0 = fmaf(r0, fmaf(-dd, r0, 1.0f), r0);           // Newton: ~0.5 ulp divide
    return 1.0f - num * r0;
}

__global__ __launch_bounds__(256) void sacl_partial(
    const float* __restrict__ pred, const float* __restrict__ target,
    double* __restrict__ partial, int n) {
    int tid = blockIdx.x * blockDim.x + threadIdx.x;
    int nth = gridDim.x * blockDim.x;

    float acc = 0.0f;
    int nv = n >> 2;
    const float4* p4v = (const float4*)pred;
    const float4* t4v = (const float4*)target;
    for (int i = tid; i < nv; i += nth) {
        float4 pv = p4v[i];
        float4 tv = t4v[i];
        acc += elem_loss(pv.x, tv.x);
        acc += elem_loss(pv.y, tv.y);
        acc += elem_loss(pv.z, tv.z);
        acc += elem_loss(pv.w, tv.w);
    }
    for (int i = (nv << 2) + tid; i < n; i += nth)  // tail (none for B=4M)
        acc += elem_loss(pred[i], target[i]);

    // wave64 reduce
#pragma unroll
    for (int off = 32; off > 0; off >>= 1) acc += __shfl_down(acc, off, 64);

    __shared__ float part[4];
    int lane = threadIdx.x & 63;
    int wid = threadIdx.x >> 6;
    if (lane == 0) part[wid] = acc;
    __syncthreads();

    if (threadIdx.x == 0) {
        partial[blockIdx.x] =
            (double)part[0] + (double)part[1] + (double)part[2] + (double)part[3];
    }
}

__global__ __launch_bounds__(256) void sacl_final(
    const double* __restrict__ partial, int g, float* __restrict__ out, int n) {
    double s = 0.0;
    for (int i = threadIdx.x; i < g; i += 256) s += partial[i];

#pragma unroll
    for (int off = 32; off > 0; off >>= 1) s += __shfl_down(s, off, 64);

    __shared__ double sm[4];
    int lane = threadIdx.x & 63;
    int wid = threadIdx.x >> 6;
    if (lane == 0) sm[wid] = s;
    __syncthreads();

    if (threadIdx.x == 0)
        out[0] = (float)((sm[0] + sm[1] + sm[2] + sm[3]) / (double)n);
}

extern "C" void kernel_launch(void* const* d_in, const int* in_sizes, int n_in,
                              void* d_out, int out_size, void* d_ws, size_t ws_size,
                              hipStream_t stream) {
    const float* pred = (const float*)d_in[0];
    const float* target = (const float*)d_in[1];
    int n = in_sizes[0];
    float* out = (float*)d_out;
    double* partial = (double*)d_ws;  // grid doubles; every slot written before read

    const int block = 256;
    const int grid = 1024;  // 4 float4-iters/thread; fewer blocks, fewer partials
    sacl_partial<<<grid, block, 0, stream>>>(pred, target, partial, n);
    sacl_final<<<1, block, 0, stream>>>(partial, grid, out, n);
}